// Round 1
// baseline (654.064 us; speedup 1.0000x reference)
//
#include <hip/hip_runtime.h>
#include <math.h>

// Problem constants
#define BATCH 64
#define HH 512
#define WW 512
#define KPOOL 31
#define PAD 15
#define NELEM ((size_t)BATCH * HH * WW)
#define INV_KK (1.0f / 961.0f)

// acc layout (doubles): [0] = bce sum, [1..64] = inter[b], [65..128] = union[b]
#define ACC_DOUBLES 129

// ---------------------------------------------------------------------------
// Kernel 1: vertical sliding-window sum of mask along H.
// One thread per (b, w) column; coalesced across w.
// ---------------------------------------------------------------------------
__global__ void vpass_kernel(const float* __restrict__ mask, float* __restrict__ vsum) {
    int tid = blockIdx.x * blockDim.x + threadIdx.x;
    if (tid >= BATCH * WW) return;
    int b = tid / WW;
    int w = tid % WW;
    const float* col = mask + (size_t)b * HH * WW + w;
    float* out = vsum + (size_t)b * HH * WW + w;

    float run = 0.0f;
    #pragma unroll
    for (int y = 0; y <= PAD; ++y) run += col[(size_t)y * WW];   // window for h=0: rows [0,15]

    for (int h = 0; h < HH; ++h) {
        out[(size_t)h * WW] = run;
        int add = h + PAD + 1;
        if (add < HH) run += col[(size_t)add * WW];
        int sub = h - PAD;
        if (sub >= 0) run -= col[(size_t)sub * WW];
    }
}

// ---------------------------------------------------------------------------
// Shared device function: given the vertical-sum row in LDS, do the horizontal
// 31-window, compute weit/bce/sigmoid terms, block-reduce, atomically add.
// blockDim.x == 256 (4 waves).
// ---------------------------------------------------------------------------
__device__ __forceinline__ float wave_reduce(float v) {
    #pragma unroll
    for (int off = 32; off; off >>= 1) v += __shfl_down(v, off, 64);
    return v;
}

__device__ void row_loss_body(const float* __restrict__ pred,
                              const float* __restrict__ mask,
                              const float* __restrict__ vrow,   // LDS, 512 floats
                              int b, int h,
                              double* __restrict__ acc) {
    size_t base = ((size_t)b * HH + h) * WW;
    float bce_p = 0.0f, inter_p = 0.0f, uni_p = 0.0f;

    for (int w = threadIdx.x; w < WW; w += 256) {
        int lo = w - PAD; if (lo < 0) lo = 0;
        int hi = w + PAD; if (hi > WW - 1) hi = WW - 1;
        float s = 0.0f;
        for (int k = lo; k <= hi; ++k) s += vrow[k];

        float m  = mask[base + w];
        float pr = pred[base + w];

        float weit = 1.0f + 5.0f * fabsf(s * INV_KK - m);
        // stable bce-with-logits: max(x,0) - x*y + log1p(exp(-|x|))
        float bce = fmaxf(pr, 0.0f) - pr * m + log1pf(expf(-fabsf(pr)));
        float p = 1.0f / (1.0f + expf(-pr));

        bce_p   += bce;
        inter_p += p * m * weit;
        uni_p   += (p + m) * weit;
    }

    __shared__ float red[3][4];
    int lane = threadIdx.x & 63;
    int wid  = threadIdx.x >> 6;
    bce_p   = wave_reduce(bce_p);
    inter_p = wave_reduce(inter_p);
    uni_p   = wave_reduce(uni_p);
    if (lane == 0) { red[0][wid] = bce_p; red[1][wid] = inter_p; red[2][wid] = uni_p; }
    __syncthreads();
    if (threadIdx.x == 0) {
        float bt = red[0][0] + red[0][1] + red[0][2] + red[0][3];
        float it = red[1][0] + red[1][1] + red[1][2] + red[1][3];
        float ut = red[2][0] + red[2][1] + red[2][2] + red[2][3];
        atomicAdd(&acc[0], (double)bt);
        atomicAdd(&acc[1 + b], (double)it);
        atomicAdd(&acc[65 + b], (double)ut);
    }
}

// ---------------------------------------------------------------------------
// Kernel 2a (fast path): row pass reading precomputed vsum.
// One block per (b, h) row.
// ---------------------------------------------------------------------------
__global__ __launch_bounds__(256) void rowpass_kernel(const float* __restrict__ pred,
                                                      const float* __restrict__ mask,
                                                      const float* __restrict__ vsum,
                                                      double* __restrict__ acc) {
    __shared__ float vrow[WW];
    int b = blockIdx.x / HH;
    int h = blockIdx.x % HH;
    size_t base = ((size_t)b * HH + h) * WW;
    for (int w = threadIdx.x; w < WW; w += 256) vrow[w] = vsum[base + w];
    __syncthreads();
    row_loss_body(pred, mask, vrow, b, h, acc);
}

// ---------------------------------------------------------------------------
// Kernel 2b (fallback if ws too small): recompute vertical window from mask.
// ---------------------------------------------------------------------------
__global__ __launch_bounds__(256) void rowpass_nows_kernel(const float* __restrict__ pred,
                                                           const float* __restrict__ mask,
                                                           double* __restrict__ acc) {
    __shared__ float vrow[WW];
    int b = blockIdx.x / HH;
    int h = blockIdx.x % HH;
    int lo = h - PAD; if (lo < 0) lo = 0;
    int hi = h + PAD; if (hi > HH - 1) hi = HH - 1;
    float s0 = 0.0f, s1 = 0.0f;
    const float* mb = mask + (size_t)b * HH * WW;
    for (int y = lo; y <= hi; ++y) {
        s0 += mb[(size_t)y * WW + threadIdx.x];
        s1 += mb[(size_t)y * WW + threadIdx.x + 256];
    }
    vrow[threadIdx.x]       = s0;
    vrow[threadIdx.x + 256] = s1;
    __syncthreads();
    row_loss_body(pred, mask, vrow, b, h, acc);
}

// ---------------------------------------------------------------------------
// Kernel 3: finalize. inter/union -> wiou per batch, mean, + wbce.
// ---------------------------------------------------------------------------
__global__ void finalize_kernel(const double* __restrict__ acc, float* __restrict__ out) {
    int b = threadIdx.x;  // 64 threads, one wave
    double inter = acc[1 + b];
    double uni   = acc[65 + b];
    double wiou = 1.0 - (inter + 1.0) / (uni - inter + 1.0);
    #pragma unroll
    for (int off = 32; off; off >>= 1) wiou += __shfl_down(wiou, off, 64);
    if (b == 0) {
        double wbce = acc[0] / (double)NELEM;
        out[0] = (float)(wbce + wiou * (1.0 / 64.0));
    }
}

// ---------------------------------------------------------------------------
extern "C" void kernel_launch(void* const* d_in, const int* in_sizes, int n_in,
                              void* d_out, int out_size, void* d_ws, size_t ws_size,
                              hipStream_t stream) {
    const float* pred = (const float*)d_in[0];
    const float* mask = (const float*)d_in[1];
    float* out = (float*)d_out;

    const size_t vsum_bytes = NELEM * sizeof(float);          // 67,108,864
    const size_t need = vsum_bytes + ACC_DOUBLES * sizeof(double);

    if (ws_size >= need) {
        float* vsum = (float*)d_ws;
        double* acc = (double*)((char*)d_ws + vsum_bytes);
        hipMemsetAsync(acc, 0, ACC_DOUBLES * sizeof(double), stream);
        int cols = BATCH * WW;
        vpass_kernel<<<(cols + 255) / 256, 256, 0, stream>>>(mask, vsum);
        rowpass_kernel<<<BATCH * HH, 256, 0, stream>>>(pred, mask, vsum, acc);
        finalize_kernel<<<1, 64, 0, stream>>>(acc, out);
    } else {
        // fallback: no vsum buffer, recompute vertical sums in-kernel
        double* acc = (double*)d_ws;
        hipMemsetAsync(acc, 0, ACC_DOUBLES * sizeof(double), stream);
        rowpass_nows_kernel<<<BATCH * HH, 256, 0, stream>>>(pred, mask, acc);
        finalize_kernel<<<1, 64, 0, stream>>>(acc, out);
    }
}

// Round 2
// 131.347 us; speedup vs baseline: 4.9797x; 4.9797x over previous
//
#include <hip/hip_runtime.h>
#include <math.h>

// Problem constants
#define BATCH 64
#define HH 512
#define WW 512
#define PAD 15
#define NELEM ((size_t)BATCH * HH * WW)
#define INV_KK (1.0f / 961.0f)

#define SEG 8                       // vertical segments per column (vpass parallelism)
#define SEGROWS (HH / SEG)          // 64 rows per segment
#define RPB 8                       // rows per rowpass block
#define NBLK (BATCH * (HH / RPB))   // 4096 rowpass blocks

// ---------------------------------------------------------------------------
// Kernel 1: vertical sliding-window sum of mask along H, segmented for occupancy.
// Thread handles one (b, w, seg): running 31-row window over its 64 output rows.
// ---------------------------------------------------------------------------
__global__ __launch_bounds__(256) void vpass_kernel(const float* __restrict__ mask,
                                                    float* __restrict__ vsum) {
    int tid = blockIdx.x * blockDim.x + threadIdx.x;
    int w   = tid & (WW - 1);
    int seg = (tid >> 9) & (SEG - 1);
    int b   = tid >> 12;                 // 512*8 = 4096 = 2^12
    if (b >= BATCH) return;
    const float* col = mask + (size_t)b * HH * WW + w;
    float* out       = vsum + (size_t)b * HH * WW + w;

    int h0 = seg * SEGROWS;
    int lo = h0 - PAD; if (lo < 0) lo = 0;
    int hi = h0 + PAD;                   // h0 <= 448 -> hi <= 463 < 512, no clip needed
    float run = 0.0f;
    for (int y = lo; y <= hi; ++y) run += col[(size_t)y * WW];

    for (int h = h0; h < h0 + SEGROWS; ++h) {
        out[(size_t)h * WW] = run;
        int add = h + PAD + 1;
        if (add < HH) run += col[(size_t)add * WW];
        int sub = h - PAD;
        if (sub >= 0) run -= col[(size_t)sub * WW];
    }
}

// ---------------------------------------------------------------------------
__device__ __forceinline__ float wave_reduce(float v) {
    #pragma unroll
    for (int off = 32; off; off >>= 1) v += __shfl_down(v, off, 64);
    return v;
}

// ---------------------------------------------------------------------------
// Kernel 2: per-row horizontal window via wave prefix-scan + loss math.
// Block = 256 threads, handles RPB=8 rows of one image. No atomics: writes
// 3 double partials per block.
// ---------------------------------------------------------------------------
__global__ __launch_bounds__(256) void rowpass_kernel(const float* __restrict__ pred,
                                                      const float* __restrict__ mask,
                                                      const float* __restrict__ vsum,
                                                      double* __restrict__ partials) {
    __shared__ float P[WW];        // inclusive prefix of the row's vertical sums
    __shared__ float segsum[8];    // per-64-elem segment totals
    __shared__ float red[3][4];

    int b  = blockIdx.x >> 6;      // HH/RPB = 64 row-groups per image
    int rg = blockIdx.x & 63;
    int h0 = rg * RPB;
    int tid  = threadIdx.x;
    int lane = tid & 63;
    int wv   = tid >> 6;

    float bce_p = 0.0f, inter_p = 0.0f, uni_p = 0.0f;

    for (int r = 0; r < RPB; ++r) {
        size_t base = ((size_t)b * HH + h0 + r) * WW;

        // --- phase 1: load + inclusive wave-scan of two 64-elem segments ---
        int i0 = wv * 64 + lane;
        int i1 = 256 + i0;
        float x0 = vsum[base + i0];
        float x1 = vsum[base + i1];
        #pragma unroll
        for (int off = 1; off < 64; off <<= 1) {
            float n0 = __shfl_up(x0, off, 64);
            float n1 = __shfl_up(x1, off, 64);
            if (lane >= off) { x0 += n0; x1 += n1; }
        }
        if (lane == 63) { segsum[wv] = x0; segsum[4 + wv] = x1; }
        __syncthreads();

        // --- phase 2: add segment offsets, publish prefix to LDS ---
        float o0 = 0.0f, o1 = 0.0f;
        #pragma unroll
        for (int j = 0; j < 8; ++j) {
            float sv = segsum[j];
            if (j < wv)     o0 += sv;
            if (j < 4 + wv) o1 += sv;
        }
        P[i0] = x0 + o0;
        P[i1] = x1 + o1;
        __syncthreads();

        // --- phase 3: window lookup + loss math for w = tid, tid+256 ---
        #pragma unroll
        for (int half = 0; half < 2; ++half) {
            int w = half * 256 + tid;
            int hiw = w + PAD; if (hiw > WW - 1) hiw = WW - 1;
            float s = P[hiw] - ((w >= PAD + 1) ? P[w - PAD - 1] : 0.0f);

            float m  = mask[base + w];
            float pr = pred[base + w];

            float weit = 1.0f + 5.0f * fabsf(s * INV_KK - m);
            float e   = expf(-fabsf(pr));
            float bce = fmaxf(pr, 0.0f) - pr * m + log1pf(e);
            float inv = 1.0f / (1.0f + e);
            float p   = (pr >= 0.0f) ? inv : e * inv;   // sigmoid(pr)

            bce_p   += bce;
            inter_p += p * m * weit;
            uni_p   += (p + m) * weit;
        }
        __syncthreads();   // protect P/segsum before next row overwrites
    }

    bce_p   = wave_reduce(bce_p);
    inter_p = wave_reduce(inter_p);
    uni_p   = wave_reduce(uni_p);
    if (lane == 0) { red[0][wv] = bce_p; red[1][wv] = inter_p; red[2][wv] = uni_p; }
    __syncthreads();
    if (tid == 0) {
        double bt = (double)red[0][0] + red[0][1] + red[0][2] + red[0][3];
        double it = (double)red[1][0] + red[1][1] + red[1][2] + red[1][3];
        double ut = (double)red[2][0] + red[2][1] + red[2][2] + red[2][3];
        partials[(size_t)blockIdx.x * 3 + 0] = bt;
        partials[(size_t)blockIdx.x * 3 + 1] = it;
        partials[(size_t)blockIdx.x * 3 + 2] = ut;
    }
}

// ---------------------------------------------------------------------------
// Kernel 3: finalize from per-block partials (no atomics anywhere).
// ---------------------------------------------------------------------------
__global__ __launch_bounds__(256) void finalize_kernel(const double* __restrict__ partials,
                                                       float* __restrict__ out) {
    __shared__ double redbce[4];
    int tid = threadIdx.x, lane = tid & 63, wv = tid >> 6;

    // global bce sum over all blocks
    double bsum = 0.0;
    for (int i = tid; i < NBLK; i += 256) bsum += partials[(size_t)i * 3 + 0];
    #pragma unroll
    for (int off = 32; off; off >>= 1) bsum += __shfl_down(bsum, off, 64);
    if (lane == 0) redbce[wv] = bsum;
    __syncthreads();

    // per-batch inter/union -> wiou (threads 0..63 = wave 0)
    double wiou_term = 0.0;
    if (tid < 64) {
        int bb = tid;
        double it = 0.0, ut = 0.0;
        for (int j = 0; j < 64; ++j) {
            it += partials[(size_t)(bb * 64 + j) * 3 + 1];
            ut += partials[(size_t)(bb * 64 + j) * 3 + 2];
        }
        wiou_term = 1.0 - (it + 1.0) / (ut - it + 1.0);
    }
    if (wv == 0) {
        #pragma unroll
        for (int off = 32; off; off >>= 1) wiou_term += __shfl_down(wiou_term, off, 64);
    }
    if (tid == 0) {
        double wbce = (redbce[0] + redbce[1] + redbce[2] + redbce[3]) / (double)NELEM;
        out[0] = (float)(wbce + wiou_term * (1.0 / 64.0));
    }
}

// ---------------------------------------------------------------------------
// Fallback path (tiny ws): recompute vertical sums in-kernel + atomics.
// ---------------------------------------------------------------------------
#define ACC_DOUBLES 129
__global__ __launch_bounds__(256) void rowpass_nows_kernel(const float* __restrict__ pred,
                                                           const float* __restrict__ mask,
                                                           double* __restrict__ acc) {
    __shared__ float vrow[WW];
    __shared__ float red[3][4];
    int b = blockIdx.x / HH;
    int h = blockIdx.x % HH;
    int lo = h - PAD; if (lo < 0) lo = 0;
    int hi = h + PAD; if (hi > HH - 1) hi = HH - 1;
    float s0 = 0.0f, s1 = 0.0f;
    const float* mb = mask + (size_t)b * HH * WW;
    for (int y = lo; y <= hi; ++y) {
        s0 += mb[(size_t)y * WW + threadIdx.x];
        s1 += mb[(size_t)y * WW + threadIdx.x + 256];
    }
    vrow[threadIdx.x]       = s0;
    vrow[threadIdx.x + 256] = s1;
    __syncthreads();

    size_t base = ((size_t)b * HH + h) * WW;
    float bce_p = 0.0f, inter_p = 0.0f, uni_p = 0.0f;
    for (int w = threadIdx.x; w < WW; w += 256) {
        int wlo = w - PAD; if (wlo < 0) wlo = 0;
        int whi = w + PAD; if (whi > WW - 1) whi = WW - 1;
        float s = 0.0f;
        for (int k = wlo; k <= whi; ++k) s += vrow[k];
        float m  = mask[base + w];
        float pr = pred[base + w];
        float weit = 1.0f + 5.0f * fabsf(s * INV_KK - m);
        float e   = expf(-fabsf(pr));
        float bce = fmaxf(pr, 0.0f) - pr * m + log1pf(e);
        float inv = 1.0f / (1.0f + e);
        float p   = (pr >= 0.0f) ? inv : e * inv;
        bce_p += bce; inter_p += p * m * weit; uni_p += (p + m) * weit;
    }
    int lane = threadIdx.x & 63, wv = threadIdx.x >> 6;
    bce_p = wave_reduce(bce_p); inter_p = wave_reduce(inter_p); uni_p = wave_reduce(uni_p);
    if (lane == 0) { red[0][wv] = bce_p; red[1][wv] = inter_p; red[2][wv] = uni_p; }
    __syncthreads();
    if (threadIdx.x == 0) {
        atomicAdd(&acc[0], (double)(red[0][0] + red[0][1] + red[0][2] + red[0][3]));
        atomicAdd(&acc[1 + b], (double)(red[1][0] + red[1][1] + red[1][2] + red[1][3]));
        atomicAdd(&acc[65 + b], (double)(red[2][0] + red[2][1] + red[2][2] + red[2][3]));
    }
}

__global__ void finalize_atomic_kernel(const double* __restrict__ acc, float* __restrict__ out) {
    int b = threadIdx.x;
    double inter = acc[1 + b];
    double uni   = acc[65 + b];
    double wiou = 1.0 - (inter + 1.0) / (uni - inter + 1.0);
    #pragma unroll
    for (int off = 32; off; off >>= 1) wiou += __shfl_down(wiou, off, 64);
    if (b == 0) {
        double wbce = acc[0] / (double)NELEM;
        out[0] = (float)(wbce + wiou * (1.0 / 64.0));
    }
}

// ---------------------------------------------------------------------------
extern "C" void kernel_launch(void* const* d_in, const int* in_sizes, int n_in,
                              void* d_out, int out_size, void* d_ws, size_t ws_size,
                              hipStream_t stream) {
    const float* pred = (const float*)d_in[0];
    const float* mask = (const float*)d_in[1];
    float* out = (float*)d_out;

    const size_t vsum_bytes = NELEM * sizeof(float);               // 64 MiB
    const size_t part_bytes = (size_t)NBLK * 3 * sizeof(double);   // 96 KiB
    const size_t need = vsum_bytes + part_bytes;

    if (ws_size >= need) {
        float*  vsum     = (float*)d_ws;
        double* partials = (double*)((char*)d_ws + vsum_bytes);
        int vthreads = BATCH * WW * SEG;                           // 262144
        vpass_kernel<<<vthreads / 256, 256, 0, stream>>>(mask, vsum);
        rowpass_kernel<<<NBLK, 256, 0, stream>>>(pred, mask, vsum, partials);
        finalize_kernel<<<1, 256, 0, stream>>>(partials, out);
    } else {
        double* acc = (double*)d_ws;
        hipMemsetAsync(acc, 0, ACC_DOUBLES * sizeof(double), stream);
        rowpass_nows_kernel<<<BATCH * HH, 256, 0, stream>>>(pred, mask, acc);
        finalize_atomic_kernel<<<1, 64, 0, stream>>>(acc, out);
    }
}

// Round 3
// 55.775 us; speedup vs baseline: 11.7268x; 2.3549x over previous
//
#include <hip/hip_runtime.h>
#include <math.h>

// Problem constants
#define BATCH 64
#define HH 512
#define WW 512
#define PAD 15
#define NELEM ((size_t)BATCH * HH * WW)
#define INV_KK (1.0f / 961.0f)

#define TILE_H 32
#define BPI (HH / TILE_H)      // 16 blocks per image
#define NBLK (BATCH * BPI)     // 1024 blocks

typedef float f4 __attribute__((ext_vector_type(4)));

__device__ __forceinline__ float wave_reduce(float v) {
    #pragma unroll
    for (int off = 32; off; off >>= 1) v += __shfl_down(v, off, 64);
    return v;
}

// ---------------------------------------------------------------------------
// Fused kernel: rolling vertical 31-window in registers -> 4 LDS rows ->
// per-wave prefix scan -> horizontal window -> loss math. No vsum in HBM.
// Block = 256 threads (4 waves), owns TILE_H=32 rows of one 512-wide image.
// ---------------------------------------------------------------------------
__global__ __launch_bounds__(256) void fused_kernel(const float* __restrict__ pred,
                                                    const float* __restrict__ mask,
                                                    double* __restrict__ partials) {
    __shared__ float vrow[4][WW];   // 4 vertical-sum rows under construction
    __shared__ float P[4][WW];      // per-wave private prefix rows
    __shared__ float red[3][4];

    const int blk  = blockIdx.x;
    const int b    = blk >> 4;          // BPI = 16
    const int tile = blk & (BPI - 1);
    const int h0   = tile * TILE_H;
    const int tid  = threadIdx.x;
    const int lane = tid & 63;
    const int wv   = tid >> 6;

    const float* mb = mask + (size_t)b * HH * WW;
    const float* pb = pred + (size_t)b * HH * WW;

    // Rolling vertical window sums for columns c0=tid, c1=tid+256.
    // Initialize window for output row h0: mask rows [max(0,h0-15), h0+15].
    const int c0 = tid, c1 = tid + 256;
    float r0 = 0.f, r1 = 0.f;
    {
        int lo = h0 - PAD; if (lo < 0) lo = 0;
        for (int y = lo; y <= h0 + PAD; ++y) {   // h0+15 <= 495 < 512 always
            r0 += mb[(size_t)y * WW + c0];
            r1 += mb[(size_t)y * WW + c1];
        }
    }

    float accb = 0.f, acci = 0.f, accu = 0.f;

    for (int it = 0; it < TILE_H / 4; ++it) {
        const int hbase = h0 + it * 4;

        // --- produce vertical-sum rows hbase..hbase+3 into LDS, slide window ---
        #pragma unroll
        for (int j = 0; j < 4; ++j) {
            const int h = hbase + j;
            vrow[j][c0] = r0;
            vrow[j][c1] = r1;
            const int add = h + PAD + 1;
            const int sub = h - PAD;
            float a0 = 0.f, a1 = 0.f, s0 = 0.f, s1 = 0.f;
            if (add < HH) { a0 = mb[(size_t)add * WW + c0]; a1 = mb[(size_t)add * WW + c1]; }
            if (sub >= 0) { s0 = mb[(size_t)sub * WW + c0]; s1 = mb[(size_t)sub * WW + c1]; }
            r0 += a0 - s0;
            r1 += a1 - s1;
        }
        __syncthreads();   // vrow ready for all waves

        // --- wave wv scans its own row hbase+wv (wave-private, no barriers) ---
        const int h = hbase + wv;
        const size_t rbase = (size_t)h * WW;

        f4 va = *(const f4*)&vrow[wv][8 * lane];
        f4 vb = *(const f4*)&vrow[wv][8 * lane + 4];
        float p0 = va.x;
        float p1 = p0 + va.y;
        float p2 = p1 + va.z;
        float p3 = p2 + va.w;
        float p4 = p3 + vb.x;
        float p5 = p4 + vb.y;
        float p6 = p5 + vb.z;
        float p7 = p6 + vb.w;
        float lanesum = p7;
        float incl = lanesum;
        #pragma unroll
        for (int off = 1; off < 64; off <<= 1) {
            float n = __shfl_up(incl, off, 64);
            if (lane >= off) incl += n;
        }
        const float excl = incl - lanesum;
        f4 Pa, Pb;
        Pa.x = excl + p0; Pa.y = excl + p1; Pa.z = excl + p2; Pa.w = excl + p3;
        Pb.x = excl + p4; Pb.y = excl + p5; Pb.z = excl + p6; Pb.w = excl + p7;
        *(f4*)&P[wv][8 * lane]     = Pa;
        *(f4*)&P[wv][8 * lane + 4] = Pb;
        __syncthreads();   // P visible; also: all waves done reading vrow

        // --- horizontal window + loss math; lane owns w = lane + 64k ---
        #pragma unroll
        for (int k = 0; k < 8; ++k) {
            const int w = lane + 64 * k;
            int hiw = w + PAD; if (hiw > WW - 1) hiw = WW - 1;
            float s = P[wv][hiw];
            if (w >= PAD + 1) s -= P[wv][w - PAD - 1];

            const float m  = mb[rbase + w];
            const float pr = pb[rbase + w];

            const float weit = 1.0f + 5.0f * fabsf(s * INV_KK - m);
            const float e    = __expf(-fabsf(pr));
            const float bce  = fmaxf(pr, 0.f) - pr * m + __logf(1.0f + e);
            const float inv  = __builtin_amdgcn_rcpf(1.0f + e);
            const float p    = (pr >= 0.f) ? inv : e * inv;   // sigmoid(pr)

            accb += bce;
            acci += p * m * weit;
            accu += (p + m) * weit;
        }
        // next iteration's vrow writes are safe: no wave reads vrow after the
        // barrier above, and P[wv] is wave-private.
    }

    accb = wave_reduce(accb);
    acci = wave_reduce(acci);
    accu = wave_reduce(accu);
    if (lane == 0) { red[0][wv] = accb; red[1][wv] = acci; red[2][wv] = accu; }
    __syncthreads();
    if (tid == 0) {
        double bt = (double)red[0][0] + red[0][1] + red[0][2] + red[0][3];
        double it = (double)red[1][0] + red[1][1] + red[1][2] + red[1][3];
        double ut = (double)red[2][0] + red[2][1] + red[2][2] + red[2][3];
        partials[(size_t)blk * 3 + 0] = bt;
        partials[(size_t)blk * 3 + 1] = it;
        partials[(size_t)blk * 3 + 2] = ut;
    }
}

// ---------------------------------------------------------------------------
// Finalize from per-block partials (1024 blocks, 16 per image).
// ---------------------------------------------------------------------------
__global__ __launch_bounds__(256) void finalize_kernel(const double* __restrict__ partials,
                                                       float* __restrict__ out) {
    __shared__ double redbce[4];
    int tid = threadIdx.x, lane = tid & 63, wv = tid >> 6;

    double bsum = 0.0;
    for (int i = tid; i < NBLK; i += 256) bsum += partials[(size_t)i * 3 + 0];
    #pragma unroll
    for (int off = 32; off; off >>= 1) bsum += __shfl_down(bsum, off, 64);
    if (lane == 0) redbce[wv] = bsum;
    __syncthreads();

    double wiou_term = 0.0;
    if (tid < 64) {
        int bb = tid;
        double it = 0.0, ut = 0.0;
        for (int j = 0; j < BPI; ++j) {
            it += partials[(size_t)(bb * BPI + j) * 3 + 1];
            ut += partials[(size_t)(bb * BPI + j) * 3 + 2];
        }
        wiou_term = 1.0 - (it + 1.0) / (ut - it + 1.0);
    }
    if (wv == 0) {
        #pragma unroll
        for (int off = 32; off; off >>= 1) wiou_term += __shfl_down(wiou_term, off, 64);
    }
    if (tid == 0) {
        double wbce = (redbce[0] + redbce[1] + redbce[2] + redbce[3]) / (double)NELEM;
        out[0] = (float)(wbce + wiou_term * (1.0 / 64.0));
    }
}

// ---------------------------------------------------------------------------
// Fallback path (tiny ws): recompute vertical sums in-kernel + atomics.
// ---------------------------------------------------------------------------
#define ACC_DOUBLES 129
__global__ __launch_bounds__(256) void rowpass_nows_kernel(const float* __restrict__ pred,
                                                           const float* __restrict__ mask,
                                                           double* __restrict__ acc) {
    __shared__ float vrow[WW];
    __shared__ float red[3][4];
    int b = blockIdx.x / HH;
    int h = blockIdx.x % HH;
    int lo = h - PAD; if (lo < 0) lo = 0;
    int hi = h + PAD; if (hi > HH - 1) hi = HH - 1;
    float s0 = 0.0f, s1 = 0.0f;
    const float* mb = mask + (size_t)b * HH * WW;
    for (int y = lo; y <= hi; ++y) {
        s0 += mb[(size_t)y * WW + threadIdx.x];
        s1 += mb[(size_t)y * WW + threadIdx.x + 256];
    }
    vrow[threadIdx.x]       = s0;
    vrow[threadIdx.x + 256] = s1;
    __syncthreads();

    size_t base = ((size_t)b * HH + h) * WW;
    float bce_p = 0.0f, inter_p = 0.0f, uni_p = 0.0f;
    for (int w = threadIdx.x; w < WW; w += 256) {
        int wlo = w - PAD; if (wlo < 0) wlo = 0;
        int whi = w + PAD; if (whi > WW - 1) whi = WW - 1;
        float s = 0.0f;
        for (int k = wlo; k <= whi; ++k) s += vrow[k];
        float m  = mask[base + w];
        float pr = pred[base + w];
        float weit = 1.0f + 5.0f * fabsf(s * INV_KK - m);
        float e   = expf(-fabsf(pr));
        float bce = fmaxf(pr, 0.0f) - pr * m + log1pf(e);
        float inv = 1.0f / (1.0f + e);
        float p   = (pr >= 0.0f) ? inv : e * inv;
        bce_p += bce; inter_p += p * m * weit; uni_p += (p + m) * weit;
    }
    int lane = threadIdx.x & 63, wvv = threadIdx.x >> 6;
    bce_p = wave_reduce(bce_p); inter_p = wave_reduce(inter_p); uni_p = wave_reduce(uni_p);
    if (lane == 0) { red[0][wvv] = bce_p; red[1][wvv] = inter_p; red[2][wvv] = uni_p; }
    __syncthreads();
    if (threadIdx.x == 0) {
        atomicAdd(&acc[0], (double)(red[0][0] + red[0][1] + red[0][2] + red[0][3]));
        atomicAdd(&acc[1 + b], (double)(red[1][0] + red[1][1] + red[1][2] + red[1][3]));
        atomicAdd(&acc[65 + b], (double)(red[2][0] + red[2][1] + red[2][2] + red[2][3]));
    }
}

__global__ void finalize_atomic_kernel(const double* __restrict__ acc, float* __restrict__ out) {
    int b = threadIdx.x;
    double inter = acc[1 + b];
    double uni   = acc[65 + b];
    double wiou = 1.0 - (inter + 1.0) / (uni - inter + 1.0);
    #pragma unroll
    for (int off = 32; off; off >>= 1) wiou += __shfl_down(wiou, off, 64);
    if (b == 0) {
        double wbce = acc[0] / (double)NELEM;
        out[0] = (float)(wbce + wiou * (1.0 / 64.0));
    }
}

// ---------------------------------------------------------------------------
extern "C" void kernel_launch(void* const* d_in, const int* in_sizes, int n_in,
                              void* d_out, int out_size, void* d_ws, size_t ws_size,
                              hipStream_t stream) {
    const float* pred = (const float*)d_in[0];
    const float* mask = (const float*)d_in[1];
    float* out = (float*)d_out;

    const size_t part_bytes = (size_t)NBLK * 3 * sizeof(double);   // 24 KiB

    if (ws_size >= part_bytes) {
        double* partials = (double*)d_ws;
        fused_kernel<<<NBLK, 256, 0, stream>>>(pred, mask, partials);
        finalize_kernel<<<1, 256, 0, stream>>>(partials, out);
    } else {
        double* acc = (double*)d_ws;
        hipMemsetAsync(acc, 0, ACC_DOUBLES * sizeof(double), stream);
        rowpass_nows_kernel<<<BATCH * HH, 256, 0, stream>>>(pred, mask, acc);
        finalize_atomic_kernel<<<1, 64, 0, stream>>>(acc, out);
    }
}